// Round 11
// baseline (485.998 us; speedup 1.0000x reference)
//
#include <hip/hip_runtime.h>
#include <hip/hip_bf16.h>

#define N_NODES 8192
#define NF      256
#define L2E     1.44269504088896341f

typedef __attribute__((ext_vector_type(8))) short short8;
typedef __attribute__((ext_vector_type(4))) short short4v;
typedef __attribute__((ext_vector_type(4))) float floatx4;

static __device__ __forceinline__ float bf2f(short s) {
    return __uint_as_float(((unsigned)(unsigned short)s) << 16);
}
static __device__ __forceinline__ short f2bf_rn(float f) {
    unsigned u = __float_as_uint(f) + 0x8000u;
    return (short)(u >> 16);
}
struct bfpair { short hi, lo; };
static __device__ __forceinline__ bfpair split_bf(float x) {
    bfpair p;
    p.hi = f2bf_rn(x);
    p.lo = f2bf_rn(x - bf2f(p.hi));
    return p;
}
// async global->LDS, 16B/lane, LDS dest = uniform base + lane*16
static __device__ __forceinline__ void async16(const void* g, void* l) {
    __builtin_amdgcn_global_load_lds(
        (const __attribute__((address_space(1))) unsigned*)g,
        (__attribute__((address_space(3))) unsigned*)l, 16, 0, 0);
}

// ---------------------------------------------------------------------------
// KX: split W (256x256 fp32) into bf16 hi/lo arrays, once.
// ---------------------------------------------------------------------------
__global__ __launch_bounds__(256) void kx_split(const float* __restrict__ W,
                                                short* __restrict__ Whi,
                                                short* __restrict__ Wlo) {
    #pragma unroll
    for (int e = 0; e < 4; ++e) {
        const int i = blockIdx.x * 1024 + e * 256 + threadIdx.x;
        bfpair p = split_bf(W[i]);
        Whi[i] = p.hi;
        Wlo[i] = p.lo;
    }
}

// ---------------------------------------------------------------------------
// K1: WhT[n][i] = sum_k X[i][k]*W[n][k] via hi/lo bf16 MFMA (fp32-accurate).
// ---------------------------------------------------------------------------
__global__ __launch_bounds__(512) void k1_gemm(const float* __restrict__ X,
                                               const short* __restrict__ Whi,
                                               const short* __restrict__ Wlo,
                                               const float* __restrict__ r,
                                               short* __restrict__ WhT,
                                               float* __restrict__ sp_src,
                                               float* __restrict__ sp_dst) {
    __shared__ float Xs[32 * 256];   // 32 KB; chunk slot = c ^ (row&7)

    const int tid = threadIdx.x;
    const int w = tid >> 6, lane = tid & 63;
    const int q = lane >> 4, m = lane & 15;
    const int rh = w >> 2, cq = w & 3;
    const int i_base = blockIdx.x * 32;

    // stage 32 rows of X (1 KB each); 4 instrs/wave
    #pragma unroll
    for (int v = 0; v < 4; ++v) {
        const int rowv = w * 4 + v;
        const int c = lane ^ (rowv & 7);
        async16(X + (size_t)(i_base + rowv) * NF + c * 4, &Xs[rowv * 256]);
    }
    __syncthreads();

    floatx4 acc[4] = {};
    const int xrow = rh * 16 + m;
    const int r7 = xrow & 7;
    #pragma unroll
    for (int ks = 0; ks < 8; ++ks) {
        const int c0 = ks * 8 + q * 2;
        float4 f0 = *(const float4*)(&Xs[xrow * 256 + ((c0 ^ r7) * 4)]);
        float4 f1 = *(const float4*)(&Xs[xrow * 256 + (((c0 + 1) ^ r7) * 4)]);
        const float xsv[8] = {f0.x, f0.y, f0.z, f0.w, f1.x, f1.y, f1.z, f1.w};
        short8 xh, xl;
        #pragma unroll
        for (int c = 0; c < 8; ++c) {
            bfpair p = split_bf(xsv[c]);
            xh[c] = p.hi; xl[c] = p.lo;
        }
        #pragma unroll
        for (int nt = 0; nt < 4; ++nt) {
            const int n = cq * 64 + nt * 16 + m;
            short8 wh = *(const short8*)(Whi + n * NF + ks * 32 + q * 8);
            short8 wl = *(const short8*)(Wlo + n * NF + ks * 32 + q * 8);
            acc[nt] = __builtin_amdgcn_mfma_f32_16x16x32_bf16(xh, wh, acc[nt], 0, 0, 0);
            acc[nt] = __builtin_amdgcn_mfma_f32_16x16x32_bf16(xl, wh, acc[nt], 0, 0, 0);
            acc[nt] = __builtin_amdgcn_mfma_f32_16x16x32_bf16(xh, wl, acc[nt], 0, 0, 0);
        }
    }

    // C/D layout: col = lane&15 (n), row = q*4 + reg (i)
    const int i0 = i_base + rh * 16 + q * 4;
    float vs[4] = {0.f, 0.f, 0.f, 0.f}, vd[4] = {0.f, 0.f, 0.f, 0.f};
    #pragma unroll
    for (int nt = 0; nt < 4; ++nt) {
        const int n = cq * 64 + nt * 16 + m;
        short4v v;
        #pragma unroll
        for (int r2 = 0; r2 < 4; ++r2) v[r2] = f2bf_rn(acc[nt][r2]);
        *(short4v*)(WhT + (size_t)n * N_NODES + i0) = v;
        const float rs = r[n], rd = r[NF + n];
        #pragma unroll
        for (int r2 = 0; r2 < 4; ++r2) {
            vs[r2] = fmaf(acc[nt][r2], rs, vs[r2]);
            vd[r2] = fmaf(acc[nt][r2], rd, vd[r2]);
        }
    }
    #pragma unroll
    for (int mask = 1; mask <= 8; mask <<= 1) {
        #pragma unroll
        for (int r2 = 0; r2 < 4; ++r2) {
            vs[r2] += __shfl_xor(vs[r2], mask);
            vd[r2] += __shfl_xor(vd[r2], mask);
        }
    }
    if (m == 0) {
        #pragma unroll
        for (int r2 = 0; r2 < 4; ++r2) {
            sp_src[cq * N_NODES + i0 + r2] = vs[r2];
            sp_dst[cq * N_NODES + i0 + r2] = vd[r2];
        }
    }
}

// ---------------------------------------------------------------------------
// K2: sum 4 partials -> s_src/s_dst; per-block max(s_dst) -> pmax[32]
// ---------------------------------------------------------------------------
__global__ __launch_bounds__(256) void k2_sv(const float* __restrict__ sp_src,
                                             const float* __restrict__ sp_dst,
                                             float* __restrict__ s_src,
                                             float* __restrict__ s_dst,
                                             float* __restrict__ pmax) {
    __shared__ float red[256];
    const int tid = threadIdx.x;
    const int i = blockIdx.x * 256 + tid;
    float ss = 0.f, sd = 0.f;
    #pragma unroll
    for (int nb = 0; nb < 4; ++nb) {
        ss += sp_src[nb * N_NODES + i];
        sd += sp_dst[nb * N_NODES + i];
    }
    s_src[i] = ss;
    s_dst[i] = sd;
    red[tid] = sd;
    __syncthreads();
    for (int off = 128; off > 0; off >>= 1) {
        if (tid < off) red[tid] = fmaxf(red[tid], red[tid + off]);
        __syncthreads();
    }
    if (tid == 0) pmax[blockIdx.x] = red[0];
}

// ---------------------------------------------------------------------------
// K4 v11: 4 INDEPENDENT barrier domains per CU (anti-lockstep).
// r10 evidence: issue utilization ~21% (65536 wave-steps x ~600 cyc = 32 us
// of work in ~150 us) with every pipe idle -> the stall is lockstep: 1-2
// barrier domains/CU means all resident waves converge and stall on the
// same ds_read->pgroup->MFMA chains together. Fix: 256-thr blocks (4 waves),
// 36 KB LDS -> 4 blocks/CU = 4 desynchronized domains.
// grid 1024 = 128 row-groups(64 rows) x 8 jh (1024 j = 32 steps x 32 j);
// wave w: 16 rows x full n=256 (acc[16], 16 MFMA/step). k3/mask DROPPED:
// A read direct (int4 x2 /lane/step, one-step prefetch, r8-proven).
// B tile [2][256][32] = 32 KB dbuf; slot swizzle q ^ ((n>>1)&3) -> 2-way
// per-16-lane phase on ds_read_b128 (free). Schedule: [4 stage DMA]->
// [2 A prefetch]->t(LDS)+pgroup+16 MFMA(setprio)->vmcnt(2) (drains DMAs,
// A rides barrier)->s_barrier. Epilogue barrier-free; 8-way atomicAdd into
// zeroed out (order-independent, exact); pden[8][8192] aliases sp_src+sp_dst.
// ---------------------------------------------------------------------------
static __device__ __forceinline__ void pgroup(const int4 a, const floatx4 t,
                                              const float s_i, const float d_i,
                                              float* p) {
    const int av[4] = {a.x, a.y, a.z, a.w};
    #pragma unroll
    for (int c = 0; c < 4; ++c) {
        float sum = s_i + t[c];
        float lr  = fmaxf(sum, 0.2f * sum);
        float pp  = __builtin_amdgcn_exp2f(fmaf(lr, L2E, d_i));
        p[c] = (av[c] != 0) ? pp : 0.0f;
    }
}

__global__ __launch_bounds__(256, 4) void k4_attn(const int* __restrict__ Adj,
                                                  const short* __restrict__ WhT,
                                                  const float* __restrict__ s_dst,
                                                  const float* __restrict__ s_src,
                                                  const float* __restrict__ pmax,
                                                  float* __restrict__ pden,
                                                  float* __restrict__ outacc) {
    __shared__ short Bs[2][256][32];    // [buf][n][32 j]; 8-short slot = c^((n>>1)&3); 32 KB
    __shared__ float ts[1024];          // this block's j-eighth of s_dst; 4 KB

    const int tid = threadIdx.x;
    const int w = tid >> 6, lane = tid & 63;
    const int q = lane >> 4, m = lane & 15;
    const int ib = blockIdx.x & 127;        // row group (64 rows)
    const int jh = blockIdx.x >> 7;         // j eighth (0..7)
    const int i0 = ib * 64;
    const int jbase = jh * 1024;
    const int row = i0 + w * 16 + m;        // wave w owns rows [w*16, w*16+16)
    const int q8 = q * 8;

    float M = pmax[0];
    #pragma unroll
    for (int b = 1; b < 32; ++b) M = fmaxf(M, pmax[b]);
    const float s_i = s_src[row];
    const float e0 = s_i + M;
    const float d_i = -fmaxf(e0, 0.2f * e0) * L2E;   // -c_i*log2e, c_i >= row max

    // ---- B staging: wave stages n-rows [w*64, w*64+64) via 4 DMA instrs ----
    // instr v: 16 rows x 64 B; lane l -> row l>>2, stored slot l&3;
    // global chunk = (l&3) ^ ((n>>1)&3)  (XOR involution, read side matches)
    const int srow = lane >> 2;
    const short* gB[4];
    #pragma unroll
    for (int v = 0; v < 4; ++v) {
        const int n = w * 64 + v * 16 + srow;
        const int c = (lane & 3) ^ ((n >> 1) & 3);
        gB[v] = WhT + (size_t)n * N_NODES + jbase + c * 8;
    }

    // ---- A pointer (per lane): 8 j per step ----
    const int* Ap = Adj + (size_t)row * N_NODES + jbase + q8;

    floatx4 acc[16];
    #pragma unroll
    for (int nt = 0; nt < 16; ++nt) acc[nt] = (floatx4){0.f, 0.f, 0.f, 0.f};
    float den = 0.f;

    // prologue: stage t-eighth (1 DMA/wave) + B step 0 + A(0)
    async16(s_dst + jbase + w * 256 + lane * 4, &ts[w * 256]);
    #pragma unroll
    for (int v = 0; v < 4; ++v)
        async16(gB[v], &Bs[0][w * 64 + v * 16][0]);
    int4 a0 = *(const int4*)(Ap);
    int4 a1 = *(const int4*)(Ap + 4);
    __syncthreads();

    for (int s = 0; s < 32; ++s) {
        const int cur = s & 1;

        // 1) stage next tile into other buffer (the 4 OLDEST vmem ops)
        short* dstb = &Bs[cur ^ 1][0][0];
        const int gn = ((s + 1) & 31) * 32;   // 32 j per step
        #pragma unroll
        for (int v = 0; v < 4; ++v)
            async16(gB[v] + gn, dstb + (w * 64 + v * 16) * 32);
        __builtin_amdgcn_sched_barrier(0);

        // 2) prefetch next step's A (the 2 NEWEST — ride across barrier)
        int4 na0 = *(const int4*)(Ap + gn);
        int4 na1 = *(const int4*)(Ap + gn + 4);
        __builtin_amdgcn_sched_barrier(0);

        // 3) t from LDS (broadcast, lgkm pipe) + P (8 j per lane)
        const int gt = s * 32;
        floatx4 t0 = *(const floatx4*)(ts + gt + q8);
        floatx4 t1 = *(const floatx4*)(ts + gt + q8 + 4);
        float p[8];
        pgroup(a0, t0, s_i, d_i, p);
        pgroup(a1, t1, s_i, d_i, p + 4);

        short8 af;
        #pragma unroll
        for (int c = 0; c < 8; ++c) { af[c] = f2bf_rn(p[c]); den += p[c]; }

        // 4) PV: 16 MFMAs (full n=256)
        const short* Bb = &Bs[cur][0][0];
        __builtin_amdgcn_s_setprio(1);
        #pragma unroll
        for (int nt = 0; nt < 16; ++nt) {
            const int n = nt * 16 + m;
            const int slot = q ^ ((n >> 1) & 3);
            short8 b = *(const short8*)(Bb + n * 32 + slot * 8);
            acc[nt] = __builtin_amdgcn_mfma_f32_16x16x32_bf16(af, b, acc[nt], 0, 0, 0);
        }
        __builtin_amdgcn_s_setprio(0);

        // 5) counted wait: drain the 4 stage DMAs; A prefetch stays in flight
        __builtin_amdgcn_sched_barrier(0);
        asm volatile("s_waitcnt vmcnt(2)" ::: "memory");
        __builtin_amdgcn_s_barrier();

        a0 = na0; a1 = na1;
    }

    // ---- epilogue: barrier-free. den: reduce over q (4 lanes per row) ----
    den += __shfl_xor(den, 16);
    den += __shfl_xor(den, 32);
    if (q == 0) pden[jh * N_NODES + row] = den;

    // out: each (row,n) owned by exactly one wave; 8-way across jh blocks
    #pragma unroll
    for (int nt = 0; nt < 16; ++nt) {
        #pragma unroll
        for (int rg = 0; rg < 4; ++rg) {
            const int orow = i0 + w * 16 + q * 4 + rg;
            const int n = nt * 16 + m;
            atomicAdd(&outacc[(size_t)orow * NF + n], acc[nt][rg]);
        }
    }
}

// ---------------------------------------------------------------------------
// K5: out = gelu(outacc / sum_{jh<8} pden[jh]), in place. 8 elems/thread.
// ---------------------------------------------------------------------------
__global__ __launch_bounds__(256) void k5_fin(const float* __restrict__ pden,
                                              float* __restrict__ out) {
    const int gid = blockIdx.x * 256 + threadIdx.x;
    const int row = gid >> 5;
    const int c0 = (gid & 31) * 8;
    const float d = ((pden[row] + pden[N_NODES + row]) +
                     (pden[2 * N_NODES + row] + pden[3 * N_NODES + row])) +
                    ((pden[4 * N_NODES + row] + pden[5 * N_NODES + row]) +
                     (pden[6 * N_NODES + row] + pden[7 * N_NODES + row]));
    const float inv = 1.0f / fmaxf(d, 1e-30f);
    float* p = out + (size_t)row * NF + c0;
    float4 v0 = *(const float4*)(p);
    float4 v1 = *(const float4*)(p + 4);
    float xs[8] = {v0.x, v0.y, v0.z, v0.w, v1.x, v1.y, v1.z, v1.w};
    #pragma unroll
    for (int c = 0; c < 8; ++c) {
        const float x = xs[c] * inv;
        xs[c] = 0.5f * x * (1.0f + erff(x * 0.70710678118f)); // exact GELU
    }
    *(float4*)(p)     = (float4){xs[0], xs[1], xs[2], xs[3]};
    *(float4*)(p + 4) = (float4){xs[4], xs[5], xs[6], xs[7]};
}

// ---------------------------------------------------------------------------
extern "C" void kernel_launch(void* const* d_in, const int* in_sizes, int n_in,
                              void* d_out, int out_size, void* d_ws, size_t ws_size,
                              hipStream_t stream) {
    const float* X = (const float*)d_in[0];   // fp32 8192x256
    const int*   A = (const int*)d_in[1];     // int32 8192x8192
    const float* W = (const float*)d_in[2];   // fp32 256x256
    const float* r = (const float*)d_in[3];   // fp32 512
    float* out = (float*)d_out;

    // ws: WhT bf16 4MB | Whi 128K | Wlo 128K | sp_src 128K | sp_dst 128K |
    //     s_src 32K | s_dst 32K | pmax 128B
    // pden (8*8192 f32 = 256K) ALIASES sp_src+sp_dst exactly (both fully
    // consumed by k2 before k4 writes pden; stream-ordered).
    char* wsp = (char*)d_ws;
    short* WhT    = (short*)wsp;                    wsp += (size_t)NF * N_NODES * 2;
    short* Whi    = (short*)wsp;                    wsp += NF * NF * 2;
    short* Wlo    = (short*)wsp;                    wsp += NF * NF * 2;
    float* sp_src = (float*)wsp;                    wsp += 4 * N_NODES * 4;
    float* sp_dst = (float*)wsp;                    wsp += 4 * N_NODES * 4;
    float* s_src  = (float*)wsp;                    wsp += N_NODES * 4;
    float* s_dst  = (float*)wsp;                    wsp += N_NODES * 4;
    float* pmax   = (float*)wsp;
    float* pden   = sp_src;                         // spans sp_src + sp_dst

    hipMemsetAsync(out, 0, (size_t)N_NODES * NF * 4, stream);
    kx_split<<<64, 256, 0, stream>>>(W, Whi, Wlo);
    k1_gemm<<<256, 512, 0, stream>>>(X, Whi, Wlo, r, WhT, sp_src, sp_dst);
    k2_sv<<<32, 256, 0, stream>>>(sp_src, sp_dst, s_src, s_dst, pmax);
    k4_attn<<<1024, 256, 0, stream>>>(A, WhT, s_dst, s_src, pmax, pden, out);
    k5_fin<<<1024, 256, 0, stream>>>(pden, out);
}

// Round 12
// 480.703 us; speedup vs baseline: 1.0110x; 1.0110x over previous
//
#include <hip/hip_runtime.h>
#include <hip/hip_bf16.h>

#define N_NODES 8192
#define NF      256
#define L2E     1.44269504088896341f

typedef __attribute__((ext_vector_type(8))) short short8;
typedef __attribute__((ext_vector_type(4))) short short4v;
typedef __attribute__((ext_vector_type(4))) float floatx4;

static __device__ __forceinline__ float bf2f(short s) {
    return __uint_as_float(((unsigned)(unsigned short)s) << 16);
}
static __device__ __forceinline__ short f2bf_rn(float f) {
    unsigned u = __float_as_uint(f) + 0x8000u;
    return (short)(u >> 16);
}
struct bfpair { short hi, lo; };
static __device__ __forceinline__ bfpair split_bf(float x) {
    bfpair p;
    p.hi = f2bf_rn(x);
    p.lo = f2bf_rn(x - bf2f(p.hi));
    return p;
}
// async global->LDS, 16B/lane, LDS dest = uniform base + lane*16
static __device__ __forceinline__ void async16(const void* g, void* l) {
    __builtin_amdgcn_global_load_lds(
        (const __attribute__((address_space(1))) unsigned*)g,
        (__attribute__((address_space(3))) unsigned*)l, 16, 0, 0);
}

// ---------------------------------------------------------------------------
// KX: split W (256x256 fp32) into bf16 hi/lo arrays, once.
// ---------------------------------------------------------------------------
__global__ __launch_bounds__(256) void kx_split(const float* __restrict__ W,
                                                short* __restrict__ Whi,
                                                short* __restrict__ Wlo) {
    #pragma unroll
    for (int e = 0; e < 4; ++e) {
        const int i = blockIdx.x * 1024 + e * 256 + threadIdx.x;
        bfpair p = split_bf(W[i]);
        Whi[i] = p.hi;
        Wlo[i] = p.lo;
    }
}

// ---------------------------------------------------------------------------
// K1 v2: WhT[n][i] = sum_k X[i][k]*W[n][k] via hi/lo bf16 MFMA.
// CHANGE vs r8: the X hi/lo split is hoisted OUT of the ks-loop. Previously
// all 4 cq-waves re-split the SAME X rows every ks iteration (~512 dup VALU
// ops/lane in the hot loop, 2 waves/SIMD to hide it). Now: each wave splits
// its 4 rows ONCE into LDS Xhi/Xlo[32][264] (row pad +8 shorts -> ds_read
// rows land 4 banks apart, <=2-way aliasing = free), then the ks-loop is
// 2 ds_read_b128 + 12 MFMA. split_bf math/values bit-identical -> Wh
// bit-identical -> downstream numerics unchanged.
// ---------------------------------------------------------------------------
__global__ __launch_bounds__(512) void k1_gemm(const float* __restrict__ X,
                                               const short* __restrict__ Whi,
                                               const short* __restrict__ Wlo,
                                               const float* __restrict__ r,
                                               short* __restrict__ WhT,
                                               float* __restrict__ sp_src,
                                               float* __restrict__ sp_dst) {
    __shared__ float Xs[32 * 256];     // 32 KB; chunk slot = c ^ (row&7)
    __shared__ short Xhi[32 * 264];    // 16.5 KB, +8 pad/row
    __shared__ short Xlo[32 * 264];

    const int tid = threadIdx.x;
    const int w = tid >> 6, lane = tid & 63;
    const int q = lane >> 4, m = lane & 15;
    const int rh = w >> 2, cq = w & 3;
    const int i_base = blockIdx.x * 32;

    // stage 32 rows of X (1 KB each); 4 instrs/wave
    #pragma unroll
    for (int v = 0; v < 4; ++v) {
        const int rowv = w * 4 + v;
        const int c = lane ^ (rowv & 7);
        async16(X + (size_t)(i_base + rowv) * NF + c * 4, &Xs[rowv * 256]);
    }
    __syncthreads();

    // split once: wave w handles rows [w*4, w*4+4); lane -> row w*4+(lane>>4),
    // 4 chunks of 4 floats at logical chunk cl, physical chunk cl^(row&7).
    {
        const int srow = w * 4 + (lane >> 4);
        const int r7s = srow & 7;
        #pragma unroll
        for (int k = 0; k < 4; ++k) {
            const int cl = (lane & 15) + k * 16;
            float4 f = *(const float4*)(&Xs[srow * 256 + ((cl ^ r7s) * 4)]);
            const float fv[4] = {f.x, f.y, f.z, f.w};
            short4v hi, lo;
            #pragma unroll
            for (int c2 = 0; c2 < 4; ++c2) {
                bfpair p = split_bf(fv[c2]);
                hi[c2] = p.hi; lo[c2] = p.lo;
            }
            *(short4v*)(&Xhi[srow * 264 + cl * 4]) = hi;
            *(short4v*)(&Xlo[srow * 264 + cl * 4]) = lo;
        }
    }
    __syncthreads();

    floatx4 acc[4] = {};
    const int xrow = rh * 16 + m;
    #pragma unroll
    for (int ks = 0; ks < 8; ++ks) {
        short8 xh = *(const short8*)(&Xhi[xrow * 264 + ks * 32 + q * 8]);
        short8 xl = *(const short8*)(&Xlo[xrow * 264 + ks * 32 + q * 8]);
        #pragma unroll
        for (int nt = 0; nt < 4; ++nt) {
            const int n = cq * 64 + nt * 16 + m;
            short8 wh = *(const short8*)(Whi + n * NF + ks * 32 + q * 8);
            short8 wl = *(const short8*)(Wlo + n * NF + ks * 32 + q * 8);
            acc[nt] = __builtin_amdgcn_mfma_f32_16x16x32_bf16(xh, wh, acc[nt], 0, 0, 0);
            acc[nt] = __builtin_amdgcn_mfma_f32_16x16x32_bf16(xl, wh, acc[nt], 0, 0, 0);
            acc[nt] = __builtin_amdgcn_mfma_f32_16x16x32_bf16(xh, wl, acc[nt], 0, 0, 0);
        }
    }

    // C/D layout: col = lane&15 (n), row = q*4 + reg (i)
    const int i0 = i_base + rh * 16 + q * 4;
    float vs[4] = {0.f, 0.f, 0.f, 0.f}, vd[4] = {0.f, 0.f, 0.f, 0.f};
    #pragma unroll
    for (int nt = 0; nt < 4; ++nt) {
        const int n = cq * 64 + nt * 16 + m;
        short4v v;
        #pragma unroll
        for (int r2 = 0; r2 < 4; ++r2) v[r2] = f2bf_rn(acc[nt][r2]);
        *(short4v*)(WhT + (size_t)n * N_NODES + i0) = v;
        const float rs = r[n], rd = r[NF + n];
        #pragma unroll
        for (int r2 = 0; r2 < 4; ++r2) {
            vs[r2] = fmaf(acc[nt][r2], rs, vs[r2]);
            vd[r2] = fmaf(acc[nt][r2], rd, vd[r2]);
        }
    }
    #pragma unroll
    for (int mask = 1; mask <= 8; mask <<= 1) {
        #pragma unroll
        for (int r2 = 0; r2 < 4; ++r2) {
            vs[r2] += __shfl_xor(vs[r2], mask);
            vd[r2] += __shfl_xor(vd[r2], mask);
        }
    }
    if (m == 0) {
        #pragma unroll
        for (int r2 = 0; r2 < 4; ++r2) {
            sp_src[cq * N_NODES + i0 + r2] = vs[r2];
            sp_dst[cq * N_NODES + i0 + r2] = vd[r2];
        }
    }
}

// ---------------------------------------------------------------------------
// K2: sum 4 partials -> s_src/s_dst; per-block max(s_dst) -> pmax[32].
// Also zeroes `out` (8 MB) — replaces the separate hipMemsetAsync dispatch
// (stream-ordered before k4's atomicAdds; no dependency on k2's main work).
// ---------------------------------------------------------------------------
__global__ __launch_bounds__(256) void k2_sv(const float* __restrict__ sp_src,
                                             const float* __restrict__ sp_dst,
                                             float* __restrict__ s_src,
                                             float* __restrict__ s_dst,
                                             float* __restrict__ pmax,
                                             float* __restrict__ out) {
    __shared__ float red[256];
    const int tid = threadIdx.x;
    const int i = blockIdx.x * 256 + tid;

    // zero out: 8192 threads x 64 float4 = 8 MB, coalesced
    {
        const float4 z = {0.f, 0.f, 0.f, 0.f};
        float4* po = (float4*)out;
        #pragma unroll 8
        for (int k = 0; k < 64; ++k)
            po[(size_t)k * 8192 + i] = z;
    }

    float ss = 0.f, sd = 0.f;
    #pragma unroll
    for (int nb = 0; nb < 4; ++nb) {
        ss += sp_src[nb * N_NODES + i];
        sd += sp_dst[nb * N_NODES + i];
    }
    s_src[i] = ss;
    s_dst[i] = sd;
    red[tid] = sd;
    __syncthreads();
    for (int off = 128; off > 0; off >>= 1) {
        if (tid < off) red[tid] = fmaxf(red[tid], red[tid + off]);
        __syncthreads();
    }
    if (tid == 0) pmax[blockIdx.x] = red[0];
}

// ---------------------------------------------------------------------------
// K4 (r8 verbatim — best measured: 183 us, total 476.9): 64-row tiles in
// 8-wave domains. grid 512 = 128 rg x 4 jh (2048 j = 32 steps x 64).
// 512 thr = 8 waves (rh4 x ch2); per wave 16 rows x 128 n x 64 j, 16 MFMA.
// Schedule: [4 t (oldest)]->[4 stage DMA]->[4 A prefetch (newest)]->pgroup
// ->MFMA(setprio)->vmcnt(4) (drains DMAs, A rides)->s_barrier.
// Epilogue barrier-free; exactly-4-way f32 atomicAdd into zeroed out.
// ---------------------------------------------------------------------------
static __device__ __forceinline__ void pgroup(const int4 a, const floatx4 t,
                                              const float s_i, const float d_i,
                                              float* p) {
    const int av[4] = {a.x, a.y, a.z, a.w};
    #pragma unroll
    for (int c = 0; c < 4; ++c) {
        float sum = s_i + t[c];
        float lr  = fmaxf(sum, 0.2f * sum);
        float pp  = __builtin_amdgcn_exp2f(fmaf(lr, L2E, d_i));
        p[c] = (av[c] != 0) ? pp : 0.0f;
    }
}

__global__ __launch_bounds__(512, 4) void k4_attn(const int* __restrict__ Adj,
                                                  const short* __restrict__ WhT,
                                                  const float* __restrict__ s_dst,
                                                  const float* __restrict__ s_src,
                                                  const float* __restrict__ pmax,
                                                  float* __restrict__ pden,
                                                  float* __restrict__ outacc) {
    __shared__ short Bs[2][256][64];    // [buf][n][64 j]; 16B slot = c^(n&7); 64 KB

    const int tid = threadIdx.x;
    const int w = tid >> 6, lane = tid & 63;
    const int q = lane >> 4, m = lane & 15;
    const int rh = w >> 1, ch = w & 1;      // 4 rowgroups x 2 n-halves
    const int ib = blockIdx.x & 127;        // row group (64 rows)
    const int jh = blockIdx.x >> 7;         // j quarter (0..3)
    const int i0 = ib * 64;
    const int jbase = jh * 2048;
    const int row = i0 + rh * 16 + m;

    float M = pmax[0];
    #pragma unroll
    for (int b = 1; b < 32; ++b) M = fmaxf(M, pmax[b]);
    const float s_i = s_src[row];
    const float e0 = s_i + M;
    const float d_i = -fmaxf(e0, 0.2f * e0) * L2E;   // -c_i*log2e, c_i >= row max

    // ---- B staging: wave stages n-rows [w*32, w*32+32) via 4 DMA instrs ----
    const int srow = lane >> 3;
    const int scc = (lane & 7) ^ srow;
    const short* gB[4];
    #pragma unroll
    for (int v = 0; v < 4; ++v)
        gB[v] = WhT + (size_t)(w * 32 + v * 8 + srow) * N_NODES + jbase + scc * 8;

    // ---- A / t pointers (per lane): 16 j per lane per step (2 k-slices) ----
    const int* Ap = Adj + (size_t)row * N_NODES + jbase + q * 8;
    const float* tp = s_dst + jbase + q * 8;

    floatx4 acc[8];
    #pragma unroll
    for (int nt = 0; nt < 8; ++nt) acc[nt] = (floatx4){0.f, 0.f, 0.f, 0.f};
    float den = 0.f;

    // prologue: stage step 0 into buf 0, prefetch A(0)
    #pragma unroll
    for (int v = 0; v < 4; ++v)
        async16(gB[v], &Bs[0][w * 32 + v * 8][0]);
    int4 a0 = *(const int4*)(Ap);
    int4 a1 = *(const int4*)(Ap + 4);
    int4 a2 = *(const int4*)(Ap + 32);
    int4 a3 = *(const int4*)(Ap + 36);
    __syncthreads();

    for (int s = 0; s < 32; ++s) {
        const int cur = s & 1;
        const int gt = s * 64;

        // 1) t loads for THIS step (the 4 OLDEST vmem ops; L2-hot broadcast)
        floatx4 t0 = *(const floatx4*)(tp + gt);
        floatx4 t1 = *(const floatx4*)(tp + gt + 4);
        floatx4 t2 = *(const floatx4*)(tp + gt + 32);
        floatx4 t3 = *(const floatx4*)(tp + gt + 36);
        __builtin_amdgcn_sched_barrier(0);

        // 2) stage next tile into other buffer (middle 4 vmem ops)
        short* dstb = &Bs[cur ^ 1][0][0];
        const int gn = ((s + 1) & 31) * 64;
        #pragma unroll
        for (int v = 0; v < 4; ++v)
            async16(gB[v] + gn, dstb + (w * 32 + v * 8) * 64);
        __builtin_amdgcn_sched_barrier(0);

        // 3) prefetch next step's A (HBM; the 4 NEWEST — ride across barrier)
        int4 na0 = *(const int4*)(Ap + gn);
        int4 na1 = *(const int4*)(Ap + gn + 4);
        int4 na2 = *(const int4*)(Ap + gn + 32);
        int4 na3 = *(const int4*)(Ap + gn + 36);
        __builtin_amdgcn_sched_barrier(0);

        // 4) P: 16 j per lane (slice0 j=q*8+0..7, slice1 j=32+q*8+0..7)
        float p[16];
        pgroup(a0, t0, s_i, d_i, p);
        pgroup(a1, t1, s_i, d_i, p + 4);
        pgroup(a2, t2, s_i, d_i, p + 8);
        pgroup(a3, t3, s_i, d_i, p + 12);

        short8 af0, af1;
        #pragma unroll
        for (int c = 0; c < 8; ++c) { af0[c] = f2bf_rn(p[c]); af1[c] = f2bf_rn(p[8 + c]); }
        #pragma unroll
        for (int c = 0; c < 16; ++c) den += p[c];

        // 5) PV: 8 nt x 2 k-slices = 16 MFMAs
        const short* Bb = &Bs[cur][0][0];
        __builtin_amdgcn_s_setprio(1);
        #pragma unroll
        for (int nt = 0; nt < 8; ++nt) {
            const int n = ch * 128 + nt * 16 + m;
            const int sw = m & 7;
            short8 b0 = *(const short8*)(Bb + n * 64 + ((q ^ sw) * 8));
            short8 b1 = *(const short8*)(Bb + n * 64 + (((4 + q) ^ sw) * 8));
            acc[nt] = __builtin_amdgcn_mfma_f32_16x16x32_bf16(af0, b0, acc[nt], 0, 0, 0);
            acc[nt] = __builtin_amdgcn_mfma_f32_16x16x32_bf16(af1, b1, acc[nt], 0, 0, 0);
        }
        __builtin_amdgcn_s_setprio(0);

        // 6) counted wait: drain the 4 stage DMAs; A-prefetch stays in flight
        __builtin_amdgcn_sched_barrier(0);
        asm volatile("s_waitcnt vmcnt(4)" ::: "memory");
        __builtin_amdgcn_s_barrier();

        a0 = na0; a1 = na1; a2 = na2; a3 = na3;
    }

    // ---- epilogue: barrier-free. den: reduce over q (4 lanes per row) ----
    den += __shfl_xor(den, 16);
    den += __shfl_xor(den, 32);
    if (ch == 0 && q == 0) pden[jh * N_NODES + row] = den;

    // out: each (row,n) owned by exactly one wave here; 4-way across jh blocks
    #pragma unroll
    for (int nt = 0; nt < 8; ++nt) {
        #pragma unroll
        for (int rg = 0; rg < 4; ++rg) {
            const int orow = i0 + rh * 16 + q * 4 + rg;
            const int n = ch * 128 + nt * 16 + m;
            atomicAdd(&outacc[(size_t)orow * NF + n], acc[nt][rg]);
        }
    }
}

// ---------------------------------------------------------------------------
// K5: out = gelu(outacc / sum_{jh<4} pden[jh]), in place. 8 elems/thread.
// ---------------------------------------------------------------------------
__global__ __launch_bounds__(256) void k5_fin(const float* __restrict__ pden,
                                              float* __restrict__ out) {
    const int gid = blockIdx.x * 256 + threadIdx.x;
    const int row = gid >> 5;
    const int c0 = (gid & 31) * 8;
    const float d = (pden[row] + pden[N_NODES + row]) +
                    (pden[2 * N_NODES + row] + pden[3 * N_NODES + row]);
    const float inv = 1.0f / fmaxf(d, 1e-30f);
    float* p = out + (size_t)row * NF + c0;
    float4 v0 = *(const float4*)(p);
    float4 v1 = *(const float4*)(p + 4);
    float xs[8] = {v0.x, v0.y, v0.z, v0.w, v1.x, v1.y, v1.z, v1.w};
    #pragma unroll
    for (int c = 0; c < 8; ++c) {
        const float x = xs[c] * inv;
        xs[c] = 0.5f * x * (1.0f + erff(x * 0.70710678118f)); // exact GELU
    }
    *(float4*)(p)     = (float4){xs[0], xs[1], xs[2], xs[3]};
    *(float4*)(p + 4) = (float4){xs[4], xs[5], xs[6], xs[7]};
}

// ---------------------------------------------------------------------------
extern "C" void kernel_launch(void* const* d_in, const int* in_sizes, int n_in,
                              void* d_out, int out_size, void* d_ws, size_t ws_size,
                              hipStream_t stream) {
    const float* X = (const float*)d_in[0];   // fp32 8192x256
    const int*   A = (const int*)d_in[1];     // int32 8192x8192
    const float* W = (const float*)d_in[2];   // fp32 256x256
    const float* r = (const float*)d_in[3];   // fp32 512
    float* out = (float*)d_out;

    // ws: WhT bf16 4MB | Whi 128K | Wlo 128K | sp_src 128K | sp_dst 128K |
    //     s_src 32K | s_dst 32K | pmax 128B
    // pden (4*8192 f32 = 128K) ALIASES sp_src (k2 consumes it before k4).
    char* wsp = (char*)d_ws;
    short* WhT    = (short*)wsp;                    wsp += (size_t)NF * N_NODES * 2;
    short* Whi    = (short*)wsp;                    wsp += NF * NF * 2;
    short* Wlo    = (short*)wsp;                    wsp += NF * NF * 2;
    float* sp_src = (float*)wsp;                    wsp += 4 * N_NODES * 4;
    float* sp_dst = (float*)wsp;                    wsp += 4 * N_NODES * 4;
    float* s_src  = (float*)wsp;                    wsp += N_NODES * 4;
    float* s_dst  = (float*)wsp;                    wsp += N_NODES * 4;
    float* pmax   = (float*)wsp;
    float* pden   = sp_src;

    kx_split<<<64, 256, 0, stream>>>(W, Whi, Wlo);
    k1_gemm<<<256, 512, 0, stream>>>(X, Whi, Wlo, r, WhT, sp_src, sp_dst);
    k2_sv<<<32, 256, 0, stream>>>(sp_src, sp_dst, s_src, s_dst, pmax, out);
    k4_attn<<<512, 512, 0, stream>>>(A, WhT, s_dst, s_src, pmax, pden, out);
    k5_fin<<<1024, 256, 0, stream>>>(pden, out);
}